// Round 8
// baseline (1378.060 us; speedup 1.0000x reference)
//
#include <hip/hip_runtime.h>
#include <math.h>

#define DIMC 64
#define C2 340
#define HID 170
#define IMG 256
#define HW 65536          // 256*256
#define ICP 384           // channels padded to 6*64

// ws float offsets (weights area), z chunk buffer follows
#define OFF_WT  0          // Wt[384 ic][64 in]  (= W_in[o(ic)][in], zero pad)     24576 f
#define OFF_KT  24576      // K4[384 ic][64 d]   ic-major (float4-friendly)        24576 f
#define OFF_WDI 49152      // wdwI[9 t][340 ic] interleaved depthwise weights       3060 f
#define OFF_WOT 52212      // WoutT[192 c][64 o] (rows >=170 zero)                 12288 f
#define OFF_Z   64500      // z chunk: [nrh*8*256 pix][340 ic] floats (adaptive)

// interleaved channel position: orig o<170 -> 2o ; o>=170 -> 2(o-170)+1
__device__ __forceinline__ int ipos(int o) { return (o < HID) ? (o << 1) : (((o - HID) << 1) + 1); }

// ---------------------------------------------------------------------------
// K_c[d1][d2] = (1/64) sum_{k1<8,k2<5} a(k2)*F[c][k1][k2]*cos(2pi(k1 d1+k2 d2)/8),
// a=1 for k2 in {0,4} else 2.  (rfft2 -> *realF -> irfft2 == circular conv by K.)
// Stored ic-major: K[ic][d], d = t1*8+t2, so per-lane float4 loads work.
// ---------------------------------------------------------------------------
__global__ void k_prep_k(const float* __restrict__ f, float* __restrict__ ws) {
    __shared__ float ct[8];
    int c = blockIdx.x;      // 0..383 (>=340 zeros the pad rows)
    int d = threadIdx.x;     // 0..63
    if (d < 8) {
        const float S = 0.70710678118654752440f;
        float v;
        switch (d) {
            case 0: v = 1.f; break;
            case 1: v = S; break;
            case 2: v = 0.f; break;
            case 3: v = -S; break;
            case 4: v = -1.f; break;
            case 5: v = -S; break;
            case 6: v = 0.f; break;
            default: v = S; break;
        }
        ct[d] = v;
    }
    __syncthreads();
    if (c >= C2) {           // pad row (ipos never maps here)
        ws[OFF_KT + (size_t)c * 64 + d] = 0.f;
        return;
    }
    int d1 = d >> 3, d2 = d & 7;
    float acc = 0.f;
    #pragma unroll
    for (int k1 = 0; k1 < 8; ++k1) {
        #pragma unroll
        for (int k2 = 0; k2 < 5; ++k2) {
            float a = (k2 == 0 || k2 == 4) ? 1.f : 2.f;
            acc += a * f[c * 40 + k1 * 5 + k2] * ct[(k1 * d1 + k2 * d2) & 7];
        }
    }
    ws[OFF_KT + (size_t)ipos(c) * 64 + d] = acc * (1.f / 64.f);
}

__global__ void k_prep_w(const float* __restrict__ Win, const float* __restrict__ Wdw,
                         const float* __restrict__ Wout, float* __restrict__ ws) {
    int t = blockIdx.x * 256 + threadIdx.x;      // grid 96*256 = 24576
    if (t < ICP * 64) {              // Wt[ic][in]
        int ic = t >> 6, in = t & 63;
        float v = 0.f;
        if (ic < C2) {
            int o = (ic & 1) ? ((ic >> 1) + HID) : (ic >> 1);
            v = Win[o * DIMC + in];
        }
        ws[OFF_WT + (size_t)t] = v;
    }
    if (t < 9 * C2) {                // wdwI (interleaved depthwise weights)
        int tt = t / C2, ic = t % C2;
        int o = (ic & 1) ? ((ic >> 1) + HID) : (ic >> 1);
        ws[OFF_WDI + tt * C2 + ic] = Wdw[o * 9 + tt];
    }
    if (t < 192 * 64) {              // WoutT (zero-padded to 192 rows)
        int c = t >> 6, o = t & 63;
        ws[OFF_WOT + t] = (c < HID) ? Wout[o * HID + c] : 0.f;
    }
}

// ---------------------------------------------------------------------------
// Fused project_in + per-channel 8x8 circular conv.  One block per patch,
// 6 waves x 64 interleaved channels; lane = channel.
//   - x patch staged to LDS [in][pix]; read as wave-uniform b128 broadcasts
//   - projection accumulates p[64 pix] in VGPRs (static indices)
//   - conv streamed ONE OUTPUT ROW per pass (8 passes): zr[8] live; K read
//     as float4 quads (1 load feeds 32 FMA -> latency hidden at 6 waves/SIMD)
//   - live set ~80 <= the RA's 84-VGPR 4-workgroup/CU target -> no spill
//   - z stores coalesced: pixel-major z[pix][ic], lanes cover contiguous 256B
// ---------------------------------------------------------------------------

// zr[d2] += K[t1][t2] * p[(D-t1)&7][(d2-t2)&7]   (all indices literal)
#define H1(D,t1,t2,d2,KC) zr[(d2)] += (KC) * p[((((D)+8-(t1))&7)<<3) + (((d2)+8-(t2))&7)];
#define H8(D,t1,t2,KC) H1(D,t1,t2,0,KC) H1(D,t1,t2,1,KC) H1(D,t1,t2,2,KC) H1(D,t1,t2,3,KC) \
                       H1(D,t1,t2,4,KC) H1(D,t1,t2,5,KC) H1(D,t1,t2,6,KC) H1(D,t1,t2,7,KC)
// quad q covers d = 4q..4q+3:  t1 = q>>1,  t2 = (q&1)*4 + j
#define HQ(D,q) { const float4 kv4 = KT4[(q)]; \
                  H8(D,(q)>>1,((q)&1)*4+0,kv4.x) H8(D,(q)>>1,((q)&1)*4+1,kv4.y) \
                  H8(D,(q)>>1,((q)&1)*4+2,kv4.z) H8(D,(q)>>1,((q)&1)*4+3,kv4.w) }
#define HPASS(D) { \
    float zr[8]; \
    zr[0]=0.f; zr[1]=0.f; zr[2]=0.f; zr[3]=0.f; zr[4]=0.f; zr[5]=0.f; zr[6]=0.f; zr[7]=0.f; \
    HQ(D,0) HQ(D,1) HQ(D,2) HQ(D,3) HQ(D,4) HQ(D,5) HQ(D,6) HQ(D,7) \
    HQ(D,8) HQ(D,9) HQ(D,10) HQ(D,11) HQ(D,12) HQ(D,13) HQ(D,14) HQ(D,15) \
    if (icv) { \
        float* zp = z + ((size_t)((pyl * 8 + (D)) * IMG + px * 8)) * C2 + ic; \
        zp[0]=zr[0]; zp[(size_t)1*C2]=zr[1]; zp[(size_t)2*C2]=zr[2]; zp[(size_t)3*C2]=zr[3]; \
        zp[(size_t)4*C2]=zr[4]; zp[(size_t)5*C2]=zr[5]; zp[(size_t)6*C2]=zr[6]; zp[(size_t)7*C2]=zr[7]; \
    } \
}

__global__ __launch_bounds__(384)
void k_proj_conv(const float* __restrict__ x,
                 const float* __restrict__ ws,
                 float* __restrict__ z,
                 int b, int pr0, int nr) {
    __shared__ float xs[64 * 64];            // [in][pix] 16 KB
    int blk = blockIdx.x;
    int pyl = blk >> 5, px = blk & 31;
    int py = pr0 + pyl;
    int tid = threadIdx.x;
    int ic = tid;                            // interleaved channel, 0..383
    bool icv = ic < C2;

    // stage x patch  [in][8x8] -> xs[in][pix]
    const float* xb = x + (size_t)b * DIMC * HW + (size_t)(py * 8) * IMG + px * 8;
    for (int u = tid; u < 1024; u += 384) {
        int in = u >> 4, rem = u & 15;
        int r = rem >> 1, h = rem & 1;
        *(float4*)&xs[in * 64 + r * 8 + h * 4] =
            *(const float4*)(xb + (size_t)in * HW + r * IMG + h * 4);
    }
    __syncthreads();

    // projection: p[pix] = sum_in Wt[ic][in] * xs[in][pix]
    float p[64];
    #pragma unroll
    for (int i = 0; i < 64; ++i) p[i] = 0.f;
    const float4* Wq = (const float4*)(ws + OFF_WT) + (size_t)ic * 16;
    for (int q = 0; q < 16; ++q) {
        float4 wv = Wq[q];                    // per-lane, L2-resident
        float wj[4] = {wv.x, wv.y, wv.z, wv.w};
        #pragma unroll
        for (int j = 0; j < 4; ++j) {
            const float4* xr = (const float4*)(xs + (q * 4 + j) * 64);
            #pragma unroll
            for (int pq = 0; pq < 16; ++pq) {
                float4 xv = xr[pq];           // wave-uniform broadcast
                p[pq * 4 + 0] += wj[j] * xv.x;
                p[pq * 4 + 1] += wj[j] * xv.y;
                p[pq * 4 + 2] += wj[j] * xv.z;
                p[pq * 4 + 3] += wj[j] * xv.w;
            }
        }
    }

    // circular 8x8 conv: 8 passes x 1 output row, K streamed as float4 quads
    const float4* KT4 = (const float4*)(ws + OFF_KT) + (size_t)ic * 16;
    HPASS(0) HPASS(1) HPASS(2) HPASS(3) HPASS(4) HPASS(5) HPASS(6) HPASS(7)
}

// ---------------------------------------------------------------------------
// Fused depthwise 3x3 (zero pad) + exact GELU-GLU + project_out GEMM.
// Per 64-ic group: stage 10x10 halo to LDS (coalesced float4), depthwise from
// LDS with register rolling (lane=ic, conflict-free), GLU via shfl_xor(1),
// then IMMEDIATE partial project_out over the group's 32 o-channels (acc[16]
// persists) -> no big gbuf, LDS 33.9 KB -> 4 blocks/CU.
// ---------------------------------------------------------------------------
__device__ __forceinline__ float gelu_exact(float v) {
    return 0.5f * v * (1.f + erff(v * 0.70710678118654752440f));
}

__global__ __launch_bounds__(256) void k_post(const float* __restrict__ z,
                                              const float* __restrict__ ws,
                                              float* __restrict__ out,
                                              int b, int tr0, int pr0h, int nrh) {
    __shared__ float zs[100 * 64];       // 10x10 halo x 64 ch, 25.6 KB
    __shared__ float gsl[32 * 65];       // group GLU slab, 8.3 KB
    int blk = blockIdx.x;
    int ty = tr0 + (blk >> 5), tx = blk & 31;
    int tid = threadIdx.x;
    int w = tid >> 6, lane = tid & 63;
    int gy0 = ty * 8, gx0 = tx * 8;
    int ybase = pr0h * 8;

    float acc[16];                        // project_out partials, lane = pixel
    #pragma unroll
    for (int k = 0; k < 16; ++k) acc[k] = 0.f;
    int ob = __builtin_amdgcn_readfirstlane(w * 16);

    for (int g = 0; g < 6; ++g) {
        int ic0 = g << 6;
        int ic = ic0 + lane;
        bool icv = ic < C2;

        __syncthreads();                  // zs/gsl free from previous group
        // --- stage 10x10 halo x 64 ch (coalesced 16B/lane) ---
        for (int u = tid; u < 1600; u += 256) {
            int pp = u >> 4;              // position 0..99
            int ch4 = (u & 15) << 2;
            int py_ = gy0 - 1 + pp / 10;
            int px_ = gx0 - 1 + pp % 10;
            float4 v = make_float4(0.f, 0.f, 0.f, 0.f);
            if ((unsigned)py_ < (unsigned)IMG && (unsigned)px_ < (unsigned)IMG &&
                (ic0 + ch4) < C2)
                v = *(const float4*)(z + ((size_t)(py_ - ybase) * IMG + px_) * C2
                                       + ic0 + ch4);
            *(float4*)&zs[pp * 64 + ch4] = v;
        }
        __syncthreads();

        // --- depthwise 3x3 + GELU-GLU; wave w -> output rows 2w, 2w+1 ---
        float wt[9];
        #pragma unroll
        for (int t = 0; t < 9; ++t)
            wt[t] = icv ? ws[OFF_WDI + t * C2 + ic] : 0.f;

        int oy0 = w * 2;
        float rr[4][10];                  // rolling rows, conflict-free ds_read
        #pragma unroll
        for (int rrow = 0; rrow < 4; ++rrow)
            #pragma unroll
            for (int cc = 0; cc < 10; ++cc)
                rr[rrow][cc] = zs[((oy0 + rrow) * 10 + cc) * 64 + lane];

        #pragma unroll
        for (int ry = 0; ry < 2; ++ry) {
            #pragma unroll
            for (int ox = 0; ox < 8; ++ox) {
                float a = wt[0] * rr[ry][ox]     + wt[1] * rr[ry][ox + 1]     + wt[2] * rr[ry][ox + 2]
                        + wt[3] * rr[ry + 1][ox] + wt[4] * rr[ry + 1][ox + 1] + wt[5] * rr[ry + 1][ox + 2]
                        + wt[6] * rr[ry + 2][ox] + wt[7] * rr[ry + 2][ox + 1] + wt[8] * rr[ry + 2][ox + 2];
                float prt = __shfl_xor(a, 1);     // partner (dw2) value
                if (!(lane & 1))                  // even lane owns o' = lane>>1
                    gsl[(lane >> 1) * 65 + (oy0 + ry) * 8 + ox] =
                        icv ? (gelu_exact(a) * prt) : 0.f;
            }
        }
        __syncthreads();

        // --- partial project_out over this group's 32 o-channels ---
        const float* wb = ws + OFF_WOT + (size_t)(g * 32) * 64 + ob;  // uniform
        #pragma unroll
        for (int cp = 0; cp < 32; ++cp) {
            float gv = gsl[cp * 65 + lane];
            const float* wp = wb + cp * 64;       // rows >=170 are zeros
            #pragma unroll
            for (int k = 0; k < 16; ++k) acc[k] += wp[k] * gv;
        }
    }

    int yy = gy0 + (lane >> 3), xx = gx0 + (lane & 7);
    #pragma unroll
    for (int k = 0; k < 16; ++k)
        out[((size_t)b * 64 + ob + k) * HW + (size_t)yy * IMG + xx] = acc[k];
}

// ---------------------------------------------------------------------------
extern "C" void kernel_launch(void* const* d_in, const int* in_sizes, int n_in,
                              void* d_out, int out_size, void* d_ws, size_t ws_size,
                              hipStream_t stream) {
    const float* x    = (const float*)d_in[0];
    const float* Win  = (const float*)d_in[1];
    const float* Wdw  = (const float*)d_in[2];
    const float* ff   = (const float*)d_in[3];
    const float* Wout = (const float*)d_in[4];
    float* out = (float*)d_out;
    float* ws  = (float*)d_ws;
    float* zbuf = ws + OFF_Z;

    hipLaunchKernelGGL(k_prep_k, dim3(ICP), dim3(64), 0, stream, ff, ws);
    hipLaunchKernelGGL(k_prep_w, dim3(96), dim3(256), 0, stream, Win, Wdw, Wout, ws);

    // Adaptive z-chunking: chunk of R patch rows needs (R+2, capped 32) rows.
    size_t capf = ws_size / sizeof(float);
    capf = (capf > OFF_Z) ? capf - OFF_Z : 0;
    const size_t perRow = (size_t)C2 * 2048;
    int R;
    if (capf >= perRow * 32) {
        R = 32;
    } else {
        long t = (long)(capf / perRow) - 2;
        R = (t < 1) ? 1 : (t > 32 ? 32 : (int)t);
    }

    for (int b = 0; b < 4; ++b) {
        for (int pr = 0; pr < 32; pr += R) {
            int tr1 = (pr + R < 32) ? pr + R : 32;
            int pr0h = (pr > 0) ? pr - 1 : 0;
            int pr1h = (tr1 < 32) ? tr1 + 1 : 32;
            int nrh = pr1h - pr0h;
            int ntr = tr1 - pr;
            hipLaunchKernelGGL(k_proj_conv, dim3(nrh * 32), dim3(384), 0, stream,
                               x, ws, zbuf, b, pr0h, nrh);
            hipLaunchKernelGGL(k_post, dim3(ntr * 32), dim3(256), 0, stream,
                               zbuf, ws, out, b, pr, pr0h, nrh);
        }
    }
}

// Round 10
// 934.236 us; speedup vs baseline: 1.4751x; 1.4751x over previous
//
#include <hip/hip_runtime.h>
#include <math.h>

#define DIMC 64
#define C2 340
#define HID 170
#define IMG 256
#define HW 65536          // 256*256
#define ICP 384           // channels padded to 6*64

// ws float offsets (weights area), z chunk buffer follows
#define OFF_WT  0          // Wt[384 ic][64 in]  (= W_in[o(ic)][in], zero pad)     24576 f
#define OFF_KT  24576      // KT[64 d][384 ic]   TRANSPOSED, cols >=340 zero       24576 f
#define OFF_WDI 49152      // wdwI[9 t][340 ic] interleaved depthwise weights       3060 f
#define OFF_WOT 52212      // WoutT[192 c][64 o] (rows >=170 zero)                 12288 f
#define OFF_Z   64500      // z chunk: [nrh*8*256 pix][340 ic] floats (adaptive)

// interleaved channel position: orig o<170 -> 2o ; o>=170 -> 2(o-170)+1
__device__ __forceinline__ int ipos(int o) { return (o < HID) ? (o << 1) : (((o - HID) << 1) + 1); }

// ---------------------------------------------------------------------------
// K_c[d1][d2] = (1/64) sum_{k1<8,k2<5} a(k2)*F[c][k1][k2]*cos(2pi(k1 d1+k2 d2)/8),
// a=1 for k2 in {0,4} else 2.  (rfft2 -> *realF -> irfft2 == circular conv by K.)
// Stored TRANSPOSED: KT[d][ic] so lane=ic kernel loads are coalesced b32 —
// and, critically, NOT float4-vectorizable (round 8: float4 K loads got
// LICM-hoisted into 64 live regs -> giant spill).
// ---------------------------------------------------------------------------
__global__ void k_prep_k(const float* __restrict__ f, float* __restrict__ ws) {
    __shared__ float ct[8];
    int c = blockIdx.x;      // 0..383 (>=340 zeros the pad columns)
    int d = threadIdx.x;     // 0..63
    if (d < 8) {
        const float S = 0.70710678118654752440f;
        float v;
        switch (d) {
            case 0: v = 1.f; break;
            case 1: v = S; break;
            case 2: v = 0.f; break;
            case 3: v = -S; break;
            case 4: v = -1.f; break;
            case 5: v = -S; break;
            case 6: v = 0.f; break;
            default: v = S; break;
        }
        ct[d] = v;
    }
    __syncthreads();
    if (c >= C2) {           // pad column (ipos never maps here)
        ws[OFF_KT + (size_t)d * ICP + c] = 0.f;
        return;
    }
    int d1 = d >> 3, d2 = d & 7;
    float acc = 0.f;
    #pragma unroll
    for (int k1 = 0; k1 < 8; ++k1) {
        #pragma unroll
        for (int k2 = 0; k2 < 5; ++k2) {
            float a = (k2 == 0 || k2 == 4) ? 1.f : 2.f;
            acc += a * f[c * 40 + k1 * 5 + k2] * ct[(k1 * d1 + k2 * d2) & 7];
        }
    }
    ws[OFF_KT + (size_t)d * ICP + ipos(c)] = acc * (1.f / 64.f);
}

__global__ void k_prep_w(const float* __restrict__ Win, const float* __restrict__ Wdw,
                         const float* __restrict__ Wout, float* __restrict__ ws) {
    int t = blockIdx.x * 256 + threadIdx.x;      // grid 96*256 = 24576
    if (t < ICP * 64) {              // Wt[ic][in]
        int ic = t >> 6, in = t & 63;
        float v = 0.f;
        if (ic < C2) {
            int o = (ic & 1) ? ((ic >> 1) + HID) : (ic >> 1);
            v = Win[o * DIMC + in];
        }
        ws[OFF_WT + (size_t)t] = v;
    }
    if (t < 9 * C2) {                // wdwI (interleaved depthwise weights)
        int tt = t / C2, ic = t % C2;
        int o = (ic & 1) ? ((ic >> 1) + HID) : (ic >> 1);
        ws[OFF_WDI + tt * C2 + ic] = Wdw[o * 9 + tt];
    }
    if (t < 192 * 64) {              // WoutT (zero-padded to 192 rows)
        int c = t >> 6, o = t & 63;
        ws[OFF_WOT + t] = (c < HID) ? Wout[o * HID + c] : 0.f;
    }
}

// ---------------------------------------------------------------------------
// Fused project_in + per-channel 8x8 circular conv.  One block per patch,
// 6 waves x 64 interleaved channels; lane = channel.
//   - x patch staged to LDS [in][pix]; read as wave-uniform b128 broadcasts
//   - projection accumulates p[64 pix] in VGPRs (static indices)
//   - conv: ONE output row per pass (8 passes), zr[8] live, K streamed as
//     per-tap b32 loads (coalesced, L2-resident).  Live set ~76 < the RA's
//     84-VGPR 4-workgroup/CU target -> no spill.
//   - memory clobber between passes: forbids LICM/CSE hoisting K loads
//     across passes (round-8 failure mode: hoisted K -> 140 live -> spill)
//   - z stores coalesced: pixel-major z[pix][ic], lanes cover contiguous 256B
// ---------------------------------------------------------------------------

// zr[d2] += K[t1][t2] * p[(D-t1)&7][(d2-t2)&7]   (all indices literal)
#define J1(D,t1,t2,d2) zr[(d2)] += kv * p[((((D)+8-(t1))&7)<<3) + (((d2)+8-(t2))&7)];
#define J8(D,t1,t2) { const float kv = KTb[(size_t)((t1)*8+(t2)) * ICP]; \
                      J1(D,t1,t2,0) J1(D,t1,t2,1) J1(D,t1,t2,2) J1(D,t1,t2,3) \
                      J1(D,t1,t2,4) J1(D,t1,t2,5) J1(D,t1,t2,6) J1(D,t1,t2,7) }
#define JROW(D,t1) J8(D,t1,0) J8(D,t1,1) J8(D,t1,2) J8(D,t1,3) \
                   J8(D,t1,4) J8(D,t1,5) J8(D,t1,6) J8(D,t1,7)
#define JPASS(D) { \
    float zr[8]; \
    zr[0]=0.f; zr[1]=0.f; zr[2]=0.f; zr[3]=0.f; zr[4]=0.f; zr[5]=0.f; zr[6]=0.f; zr[7]=0.f; \
    JROW(D,0) JROW(D,1) JROW(D,2) JROW(D,3) JROW(D,4) JROW(D,5) JROW(D,6) JROW(D,7) \
    if (icv) { \
        float* zp = z + ((size_t)((pyl * 8 + (D)) * IMG + px * 8)) * C2 + ic; \
        zp[0]=zr[0]; zp[(size_t)1*C2]=zr[1]; zp[(size_t)2*C2]=zr[2]; zp[(size_t)3*C2]=zr[3]; \
        zp[(size_t)4*C2]=zr[4]; zp[(size_t)5*C2]=zr[5]; zp[(size_t)6*C2]=zr[6]; zp[(size_t)7*C2]=zr[7]; \
    } \
    asm volatile("" ::: "memory"); \
}

__global__ __launch_bounds__(384)
void k_proj_conv(const float* __restrict__ x,
                 const float* __restrict__ ws,
                 float* __restrict__ z,
                 int b, int pr0, int nr) {
    __shared__ float xs[64 * 64];            // [in][pix] 16 KB
    int blk = blockIdx.x;
    int pyl = blk >> 5, px = blk & 31;
    int py = pr0 + pyl;
    int tid = threadIdx.x;
    int ic = tid;                            // interleaved channel, 0..383
    bool icv = ic < C2;

    // stage x patch  [in][8x8] -> xs[in][pix]
    const float* xb = x + (size_t)b * DIMC * HW + (size_t)(py * 8) * IMG + px * 8;
    for (int u = tid; u < 1024; u += 384) {
        int in = u >> 4, rem = u & 15;
        int r = rem >> 1, h = rem & 1;
        *(float4*)&xs[in * 64 + r * 8 + h * 4] =
            *(const float4*)(xb + (size_t)in * HW + r * IMG + h * 4);
    }
    __syncthreads();

    // projection: p[pix] = sum_in Wt[ic][in] * xs[in][pix]
    float p[64];
    #pragma unroll
    for (int i = 0; i < 64; ++i) p[i] = 0.f;
    const float4* Wq = (const float4*)(ws + OFF_WT) + (size_t)ic * 16;
    for (int q = 0; q < 16; ++q) {
        float4 wv = Wq[q];                    // per-lane, L2-resident
        float wj[4] = {wv.x, wv.y, wv.z, wv.w};
        #pragma unroll
        for (int j = 0; j < 4; ++j) {
            const float4* xr = (const float4*)(xs + (q * 4 + j) * 64);
            #pragma unroll
            for (int pq = 0; pq < 16; ++pq) {
                float4 xv = xr[pq];           // wave-uniform broadcast
                p[pq * 4 + 0] += wj[j] * xv.x;
                p[pq * 4 + 1] += wj[j] * xv.y;
                p[pq * 4 + 2] += wj[j] * xv.z;
                p[pq * 4 + 3] += wj[j] * xv.w;
            }
        }
    }

    // circular 8x8 conv: 8 passes x 1 output row, K streamed per tap (b32)
    const float* KTb = ws + OFF_KT + ic;      // KT[d][ic], lane-consecutive
    JPASS(0) JPASS(1) JPASS(2) JPASS(3) JPASS(4) JPASS(5) JPASS(6) JPASS(7)
}

// ---------------------------------------------------------------------------
// Fused depthwise 3x3 (zero pad) + exact GELU-GLU + project_out GEMM.
// Per 64-ic group: stage 10x10 halo to LDS (coalesced float4), depthwise from
// LDS with register rolling (lane=ic, conflict-free), GLU via shfl_xor(1),
// then IMMEDIATE partial project_out over the group's 32 o-channels (acc[16]
// persists) -> no big gbuf, LDS 33.9 KB -> 4 blocks/CU.
// ---------------------------------------------------------------------------
__device__ __forceinline__ float gelu_exact(float v) {
    return 0.5f * v * (1.f + erff(v * 0.70710678118654752440f));
}

__global__ __launch_bounds__(256) void k_post(const float* __restrict__ z,
                                              const float* __restrict__ ws,
                                              float* __restrict__ out,
                                              int b, int tr0, int pr0h, int nrh) {
    __shared__ float zs[100 * 64];       // 10x10 halo x 64 ch, 25.6 KB
    __shared__ float gsl[32 * 65];       // group GLU slab, 8.3 KB
    int blk = blockIdx.x;
    int ty = tr0 + (blk >> 5), tx = blk & 31;
    int tid = threadIdx.x;
    int w = tid >> 6, lane = tid & 63;
    int gy0 = ty * 8, gx0 = tx * 8;
    int ybase = pr0h * 8;

    float acc[16];                        // project_out partials, lane = pixel
    #pragma unroll
    for (int k = 0; k < 16; ++k) acc[k] = 0.f;
    int ob = __builtin_amdgcn_readfirstlane(w * 16);

    for (int g = 0; g < 6; ++g) {
        int ic0 = g << 6;
        int ic = ic0 + lane;
        bool icv = ic < C2;

        __syncthreads();                  // zs/gsl free from previous group
        // --- stage 10x10 halo x 64 ch (coalesced 16B/lane) ---
        for (int u = tid; u < 1600; u += 256) {
            int pp = u >> 4;              // position 0..99
            int ch4 = (u & 15) << 2;
            int py_ = gy0 - 1 + pp / 10;
            int px_ = gx0 - 1 + pp % 10;
            float4 v = make_float4(0.f, 0.f, 0.f, 0.f);
            if ((unsigned)py_ < (unsigned)IMG && (unsigned)px_ < (unsigned)IMG &&
                (ic0 + ch4) < C2)
                v = *(const float4*)(z + ((size_t)(py_ - ybase) * IMG + px_) * C2
                                       + ic0 + ch4);
            *(float4*)&zs[pp * 64 + ch4] = v;
        }
        __syncthreads();

        // --- depthwise 3x3 + GELU-GLU; wave w -> output rows 2w, 2w+1 ---
        float wt[9];
        #pragma unroll
        for (int t = 0; t < 9; ++t)
            wt[t] = icv ? ws[OFF_WDI + t * C2 + ic] : 0.f;

        int oy0 = w * 2;
        float rr[4][10];                  // rolling rows, conflict-free ds_read
        #pragma unroll
        for (int rrow = 0; rrow < 4; ++rrow)
            #pragma unroll
            for (int cc = 0; cc < 10; ++cc)
                rr[rrow][cc] = zs[((oy0 + rrow) * 10 + cc) * 64 + lane];

        #pragma unroll
        for (int ry = 0; ry < 2; ++ry) {
            #pragma unroll
            for (int ox = 0; ox < 8; ++ox) {
                float a = wt[0] * rr[ry][ox]     + wt[1] * rr[ry][ox + 1]     + wt[2] * rr[ry][ox + 2]
                        + wt[3] * rr[ry + 1][ox] + wt[4] * rr[ry + 1][ox + 1] + wt[5] * rr[ry + 1][ox + 2]
                        + wt[6] * rr[ry + 2][ox] + wt[7] * rr[ry + 2][ox + 1] + wt[8] * rr[ry + 2][ox + 2];
                float prt = __shfl_xor(a, 1);     // partner (dw2) value
                if (!(lane & 1))                  // even lane owns o' = lane>>1
                    gsl[(lane >> 1) * 65 + (oy0 + ry) * 8 + ox] =
                        icv ? (gelu_exact(a) * prt) : 0.f;
            }
        }
        __syncthreads();

        // --- partial project_out over this group's 32 o-channels ---
        const float* wb = ws + OFF_WOT + (size_t)(g * 32) * 64 + ob;  // uniform
        #pragma unroll
        for (int cp = 0; cp < 32; ++cp) {
            float gv = gsl[cp * 65 + lane];
            const float* wp = wb + cp * 64;       // rows >=170 are zeros
            #pragma unroll
            for (int k = 0; k < 16; ++k) acc[k] += wp[k] * gv;
        }
    }

    int yy = gy0 + (lane >> 3), xx = gx0 + (lane & 7);
    #pragma unroll
    for (int k = 0; k < 16; ++k)
        out[((size_t)b * 64 + ob + k) * HW + (size_t)yy * IMG + xx] = acc[k];
}

// ---------------------------------------------------------------------------
extern "C" void kernel_launch(void* const* d_in, const int* in_sizes, int n_in,
                              void* d_out, int out_size, void* d_ws, size_t ws_size,
                              hipStream_t stream) {
    const float* x    = (const float*)d_in[0];
    const float* Win  = (const float*)d_in[1];
    const float* Wdw  = (const float*)d_in[2];
    const float* ff   = (const float*)d_in[3];
    const float* Wout = (const float*)d_in[4];
    float* out = (float*)d_out;
    float* ws  = (float*)d_ws;
    float* zbuf = ws + OFF_Z;

    hipLaunchKernelGGL(k_prep_k, dim3(ICP), dim3(64), 0, stream, ff, ws);
    hipLaunchKernelGGL(k_prep_w, dim3(96), dim3(256), 0, stream, Win, Wdw, Wout, ws);

    // Adaptive z-chunking: chunk of R patch rows needs (R+2, capped 32) rows.
    size_t capf = ws_size / sizeof(float);
    capf = (capf > OFF_Z) ? capf - OFF_Z : 0;
    const size_t perRow = (size_t)C2 * 2048;
    int R;
    if (capf >= perRow * 32) {
        R = 32;
    } else {
        long t = (long)(capf / perRow) - 2;
        R = (t < 1) ? 1 : (t > 32 ? 32 : (int)t);
    }

    for (int b = 0; b < 4; ++b) {
        for (int pr = 0; pr < 32; pr += R) {
            int tr1 = (pr + R < 32) ? pr + R : 32;
            int pr0h = (pr > 0) ? pr - 1 : 0;
            int pr1h = (tr1 < 32) ? tr1 + 1 : 32;
            int nrh = pr1h - pr0h;
            int ntr = tr1 - pr;
            hipLaunchKernelGGL(k_proj_conv, dim3(nrh * 32), dim3(384), 0, stream,
                               x, ws, zbuf, b, pr0h, nrh);
            hipLaunchKernelGGL(k_post, dim3(ntr * 32), dim3(256), 0, stream,
                               zbuf, ws, out, b, pr, pr0h, nrh);
        }
    }
}